// Round 1
// baseline (13008.179 us; speedup 1.0000x reference)
//
#include <hip/hip_runtime.h>

#define T_REL 3
#define F_IN  128
#define F_HID 128
#define F_OUT 64

// ---------------------------------------------------------------------------
// Degree kernels: deg[t][i] = 1 + indeg_t(i);  then in-place -> 1/sqrt(deg)
// ---------------------------------------------------------------------------
__global__ void init_deg_kernel(float* __restrict__ deg, int n) {
    int i = blockIdx.x * blockDim.x + threadIdx.x;
    if (i < n) deg[i] = 1.0f;
}

__global__ void accum_deg_kernel(float* __restrict__ deg,
                                 const int* __restrict__ edges,
                                 int E, int N) {
    int t = blockIdx.y;
    int e = blockIdx.x * blockDim.x + threadIdx.x;
    if (e < E) {
        int d = edges[(size_t)(t * 2 + 1) * E + e];
        atomicAdd(&deg[(size_t)t * N + d], 1.0f);
    }
}

__global__ void deg_to_dinv_kernel(float* __restrict__ deg, int n) {
    int i = blockIdx.x * blockDim.x + threadIdx.x;
    if (i < n) deg[i] = 1.0f / sqrtf(deg[i]);
}

// ---------------------------------------------------------------------------
// fp32 GEMM: H[N x BN] = act(X[N x 128]) @ W[128 x BN]
// BM=128 rows/block, full K=128 staged in LDS, 256 threads, TM=8 x TN outputs.
// ---------------------------------------------------------------------------
template<int BN, int TN, bool RELU>
__global__ __launch_bounds__(256) void gemm_kernel(
    const float* __restrict__ X, const float* __restrict__ W,
    float* __restrict__ H, int N)
{
    constexpr int BM = 128;
    constexpr int K  = 128;
    constexpr int TM = 8;
    constexpr int XS_STRIDE = K + 4;   // 132: pad so row-strided reads spread banks

    __shared__ float Xs[BM * XS_STRIDE];
    __shared__ float Ws[K * BN];

    const int tid  = threadIdx.x;
    const int row0 = blockIdx.x * BM;

    // ---- stage X tile (float4 global loads, float4 LDS stores; 132*4=528B row
    //      stride keeps 16B alignment) ----
    constexpr int XV = BM * K / 4;           // 4096 float4
    for (int i = tid; i < XV; i += 256) {
        int r  = i >> 5;                     // K/4 = 32 float4 per row
        int c4 = i & 31;
        float4 v = make_float4(0.f, 0.f, 0.f, 0.f);
        int gr = row0 + r;
        if (gr < N) {
            v = reinterpret_cast<const float4*>(X + (size_t)gr * K)[c4];
            if (RELU) {
                v.x = fmaxf(v.x, 0.f); v.y = fmaxf(v.y, 0.f);
                v.z = fmaxf(v.z, 0.f); v.w = fmaxf(v.w, 0.f);
            }
        }
        *reinterpret_cast<float4*>(&Xs[r * XS_STRIDE + c4 * 4]) = v;
    }
    // ---- stage W (row-major [K][BN], direct copy) ----
    constexpr int WV = K * BN / 4;
    {
        const float4* W4  = reinterpret_cast<const float4*>(W);
        float4*       Ws4 = reinterpret_cast<float4*>(Ws);
        for (int i = tid; i < WV; i += 256) Ws4[i] = W4[i];
    }
    __syncthreads();

    const int tx = tid & 15;                 // 16 col-groups
    const int ty = tid >> 4;                 // 16 row-groups; rows = ty + m*16

    float acc[TM][TN];
#pragma unroll
    for (int m = 0; m < TM; ++m)
#pragma unroll
        for (int n = 0; n < TN; ++n) acc[m][n] = 0.f;

#pragma unroll 4
    for (int k = 0; k < K; ++k) {
        float a[TM];
#pragma unroll
        for (int m = 0; m < TM; ++m)
            a[m] = Xs[(ty + m * 16) * XS_STRIDE + k];
        float b[TN];
        const float* wrow = &Ws[k * BN + tx * TN];
#pragma unroll
        for (int n = 0; n < TN; n += 4) {
            float4 bv = *reinterpret_cast<const float4*>(wrow + n);
            b[n] = bv.x; b[n + 1] = bv.y; b[n + 2] = bv.z; b[n + 3] = bv.w;
        }
#pragma unroll
        for (int m = 0; m < TM; ++m)
#pragma unroll
            for (int n = 0; n < TN; ++n)
                acc[m][n] = fmaf(a[m], b[n], acc[m][n]);
    }

#pragma unroll
    for (int m = 0; m < TM; ++m) {
        int gr = row0 + ty + m * 16;
        if (gr < N) {
            float* orow = H + (size_t)gr * BN + tx * TN;
#pragma unroll
            for (int n = 0; n < TN; n += 4) {
                *reinterpret_cast<float4*>(orow + n) =
                    make_float4(acc[m][n], acc[m][n + 1], acc[m][n + 2], acc[m][n + 3]);
            }
        }
    }
}

// ---------------------------------------------------------------------------
// out[i,:] += (H[i,:] * dinv[i]^2 + b[:]) / 3     (self-loop + bias, mean 1/T)
// ---------------------------------------------------------------------------
template<int F>
__global__ __launch_bounds__(256) void self_bias_kernel(
    float* __restrict__ out, const float* __restrict__ H,
    const float* __restrict__ dinv, const float* __restrict__ b, int N)
{
    constexpr int Q = F / 4;
    int idx = blockIdx.x * blockDim.x + threadIdx.x;
    if (idx >= N * Q) return;
    int i = idx / Q;
    int q = idx & (Q - 1);
    float di = dinv[i];
    float s  = di * di * (1.0f / 3.0f);
    float4 h  = reinterpret_cast<const float4*>(H)[idx];
    float4 bv = reinterpret_cast<const float4*>(b)[q];
    float4* o = reinterpret_cast<float4*>(out) + idx;
    float4 cur = *o;
    cur.x += h.x * s + bv.x * (1.0f / 3.0f);
    cur.y += h.y * s + bv.y * (1.0f / 3.0f);
    cur.z += h.z * s + bv.z * (1.0f / 3.0f);
    cur.w += h.w * s + bv.w * (1.0f / 3.0f);
    *o = cur;
}

// ---------------------------------------------------------------------------
// Edge scatter: out[dst,:] += H[src,:] * (dinv[src]*dinv[dst]/3)
// One float4 of the feature row per thread; consecutive lanes share an edge
// -> coalesced gather + consecutive-address atomics.
// ---------------------------------------------------------------------------
template<int F>
__global__ __launch_bounds__(256) void edge_scatter_kernel(
    float* __restrict__ out, const float* __restrict__ H,
    const float* __restrict__ dinv,
    const int* __restrict__ src, const int* __restrict__ dst, int E)
{
    constexpr int Q  = F / 4;
    constexpr int SH = (Q == 32) ? 5 : 4;
    int idx = blockIdx.x * blockDim.x + threadIdx.x;
    if (idx >= E * Q) return;
    int e = idx >> SH;
    int q = idx & (Q - 1);
    int s = src[e];
    int d = dst[e];
    float c = dinv[s] * dinv[d] * (1.0f / 3.0f);
    float4 v = reinterpret_cast<const float4*>(H + (size_t)s * F)[q];
    float* o = out + (size_t)d * F + q * 4;
    atomicAdd(o + 0, v.x * c);
    atomicAdd(o + 1, v.y * c);
    atomicAdd(o + 2, v.z * c);
    atomicAdd(o + 3, v.w * c);
}

// ---------------------------------------------------------------------------
extern "C" void kernel_launch(void* const* d_in, const int* in_sizes, int n_in,
                              void* d_out, int out_size, void* d_ws, size_t ws_size,
                              hipStream_t stream) {
    const float* x     = (const float*)d_in[0];
    const int*   edges = (const int*)  d_in[1];
    const float* W1    = (const float*)d_in[2];
    const float* b1    = (const float*)d_in[3];
    const float* W2    = (const float*)d_in[4];
    const float* b2    = (const float*)d_in[5];
    float* out = (float*)d_out;

    const int N = in_sizes[0] / F_IN;
    const int E = in_sizes[1] / (T_REL * 2);

    // workspace layout (floats): dinv[3N] | H[N*128] | h1[N*128]
    float* ws   = (float*)d_ws;
    size_t off  = ((size_t)(T_REL * N) + 63) & ~(size_t)63;
    float* dinv = ws;
    float* Hbuf = ws + off;
    float* h1   = Hbuf + (size_t)N * F_HID;

    const int B = 256;

    // ---- degrees (shared by both layers) ----
    init_deg_kernel<<<(T_REL * N + B - 1) / B, B, 0, stream>>>(dinv, T_REL * N);
    {
        dim3 grid((E + B - 1) / B, T_REL);
        accum_deg_kernel<<<grid, B, 0, stream>>>(dinv, edges, E, N);
    }
    deg_to_dinv_kernel<<<(T_REL * N + B - 1) / B, B, 0, stream>>>(dinv, T_REL * N);

    // ---- layer 1: h1 = mean_t( GCNConv(x@W1[t]) + b1[t] ) ----
    hipMemsetAsync(h1, 0, (size_t)N * F_HID * sizeof(float), stream);
    for (int t = 0; t < T_REL; ++t) {
        const int* src_t = edges + (size_t)(t * 2)     * E;
        const int* dst_t = edges + (size_t)(t * 2 + 1) * E;
        gemm_kernel<128, 8, false><<<(N + 127) / 128, 256, 0, stream>>>(
            x, W1 + (size_t)t * F_IN * F_HID, Hbuf, N);
        self_bias_kernel<128><<<((size_t)N * 32 + B - 1) / B, B, 0, stream>>>(
            h1, Hbuf, dinv + (size_t)t * N, b1 + (size_t)t * F_HID, N);
        edge_scatter_kernel<128><<<((size_t)E * 32 + B - 1) / B, B, 0, stream>>>(
            h1, Hbuf, dinv + (size_t)t * N, src_t, dst_t, E);
    }

    // ---- layer 2: out = mean_t( GCNConv(relu(h1)@W2[t]) + b2[t] ) ----
    hipMemsetAsync(out, 0, (size_t)N * F_OUT * sizeof(float), stream);
    for (int t = 0; t < T_REL; ++t) {
        const int* src_t = edges + (size_t)(t * 2)     * E;
        const int* dst_t = edges + (size_t)(t * 2 + 1) * E;
        gemm_kernel<64, 4, true><<<(N + 127) / 128, 256, 0, stream>>>(
            h1, W2 + (size_t)t * F_HID * F_OUT, Hbuf, N);
        self_bias_kernel<64><<<((size_t)N * 16 + B - 1) / B, B, 0, stream>>>(
            out, Hbuf, dinv + (size_t)t * N, b2 + (size_t)t * F_OUT, N);
        edge_scatter_kernel<64><<<((size_t)E * 16 + B - 1) / B, B, 0, stream>>>(
            out, Hbuf, dinv + (size_t)t * N, src_t, dst_t, E);
    }
}

// Round 2
// 1734.310 us; speedup vs baseline: 7.5005x; 7.5005x over previous
//
#include <hip/hip_runtime.h>

#define T_REL 3
#define F_IN  128
#define F_HID 128
#define F_OUT 64

// ===========================================================================
// CSR build: counts -> exclusive scan -> slot scatter (edges sorted by dst).
// Built once, reused by both layers (edge lists are layer-invariant).
// ===========================================================================

__global__ void accum_deg_kernel(int* __restrict__ counts,
                                 const int* __restrict__ edges,
                                 int E, int N) {
    int t = blockIdx.y;
    int e = blockIdx.x * blockDim.x + threadIdx.x;
    if (e < E) {
        int d = edges[(size_t)(t * 2 + 1) * E + e];
        atomicAdd(&counts[t * N + d], 1);
    }
}

__global__ void dinv_kernel(float* __restrict__ dinv,
                            const int* __restrict__ counts, int n) {
    int i = blockIdx.x * blockDim.x + threadIdx.x;
    if (i < n) dinv[i] = rsqrtf(1.0f + (float)counts[i]);
}

// --- hierarchical exclusive scan over counts[t][0..N), CHUNK=2048/block ----
__global__ __launch_bounds__(256) void scan_pass1(const int* __restrict__ counts,
                                                  int* __restrict__ partials,
                                                  int N, int nblk) {
    int t = blockIdx.y, blk = blockIdx.x, tid = threadIdx.x;
    int base = blk * 2048;
    int s = 0;
#pragma unroll
    for (int k = 0; k < 8; ++k) {
        int idx = base + tid * 8 + k;
        if (idx < N) s += counts[t * N + idx];
    }
    __shared__ int sh[256];
    sh[tid] = s;
    __syncthreads();
    for (int off = 128; off > 0; off >>= 1) {
        if (tid < off) sh[tid] += sh[tid + off];
        __syncthreads();
    }
    if (tid == 0) partials[t * nblk + blk] = sh[0];
}

__global__ void scan_partials(int* __restrict__ partials, int* __restrict__ rp,
                              int nblk, int N, int E) {
    int t = blockIdx.x;
    if (threadIdx.x == 0) {
        int run = 0;
        for (int i = 0; i < nblk; ++i) {
            int c = partials[t * nblk + i];
            partials[t * nblk + i] = run;
            run += c;
        }
        rp[(size_t)t * (N + 1) + N] = E;
    }
}

__global__ __launch_bounds__(256) void scan_pass2(const int* __restrict__ counts,
                                                  const int* __restrict__ partials,
                                                  int* __restrict__ rp,
                                                  int* __restrict__ cursor,
                                                  int N, int nblk) {
    int t = blockIdx.y, blk = blockIdx.x, tid = threadIdx.x;
    int base = blk * 2048;
    int v[8], pref[8];
    int run = 0;
#pragma unroll
    for (int k = 0; k < 8; ++k) {
        int idx = base + tid * 8 + k;
        v[k] = (idx < N) ? counts[t * N + idx] : 0;
        pref[k] = run;
        run += v[k];
    }
    __shared__ int sh[256];
    sh[tid] = run;
    __syncthreads();
    for (int off = 1; off < 256; off <<= 1) {
        int x = (tid >= off) ? sh[tid - off] : 0;
        __syncthreads();
        sh[tid] += x;
        __syncthreads();
    }
    int texcl = ((tid > 0) ? sh[tid - 1] : 0) + partials[t * nblk + blk];
#pragma unroll
    for (int k = 0; k < 8; ++k) {
        int idx = base + tid * 8 + k;
        if (idx < N) {
            int val = texcl + pref[k];
            rp[(size_t)t * (N + 1) + idx] = val;
            cursor[t * N + idx] = val;
        }
    }
}

__global__ void csr_build_kernel(int* __restrict__ cursor,
                                 int* __restrict__ srcs_out,
                                 const int* __restrict__ edges, int E, int N) {
    int t = blockIdx.y;
    int e = blockIdx.x * blockDim.x + threadIdx.x;
    if (e < E) {
        int s = edges[(size_t)(t * 2) * E + e];
        int d = edges[(size_t)(t * 2 + 1) * E + e];
        int slot = atomicAdd(&cursor[t * N + d], 1);
        srcs_out[(size_t)t * E + slot] = s;
    }
}

// ===========================================================================
// fp32 GEMM: H[N x BN] = act(X[N x 128]) @ W[128 x BN]   (unchanged from R1)
// ===========================================================================
template<int BN, int TN, bool RELU>
__global__ __launch_bounds__(256) void gemm_kernel(
    const float* __restrict__ X, const float* __restrict__ W,
    float* __restrict__ H, int N)
{
    constexpr int BM = 128;
    constexpr int K  = 128;
    constexpr int TM = 8;
    constexpr int XS_STRIDE = K + 4;

    __shared__ float Xs[BM * XS_STRIDE];
    __shared__ float Ws[K * BN];

    const int tid  = threadIdx.x;
    const int row0 = blockIdx.x * BM;

    constexpr int XV = BM * K / 4;
    for (int i = tid; i < XV; i += 256) {
        int r  = i >> 5;
        int c4 = i & 31;
        float4 v = make_float4(0.f, 0.f, 0.f, 0.f);
        int gr = row0 + r;
        if (gr < N) {
            v = reinterpret_cast<const float4*>(X + (size_t)gr * K)[c4];
            if (RELU) {
                v.x = fmaxf(v.x, 0.f); v.y = fmaxf(v.y, 0.f);
                v.z = fmaxf(v.z, 0.f); v.w = fmaxf(v.w, 0.f);
            }
        }
        *reinterpret_cast<float4*>(&Xs[r * XS_STRIDE + c4 * 4]) = v;
    }
    constexpr int WV = K * BN / 4;
    {
        const float4* W4  = reinterpret_cast<const float4*>(W);
        float4*       Ws4 = reinterpret_cast<float4*>(Ws);
        for (int i = tid; i < WV; i += 256) Ws4[i] = W4[i];
    }
    __syncthreads();

    const int tx = tid & 15;
    const int ty = tid >> 4;

    float acc[TM][TN];
#pragma unroll
    for (int m = 0; m < TM; ++m)
#pragma unroll
        for (int n = 0; n < TN; ++n) acc[m][n] = 0.f;

#pragma unroll 4
    for (int k = 0; k < K; ++k) {
        float a[TM];
#pragma unroll
        for (int m = 0; m < TM; ++m)
            a[m] = Xs[(ty + m * 16) * XS_STRIDE + k];
        float b[TN];
        const float* wrow = &Ws[k * BN + tx * TN];
#pragma unroll
        for (int n = 0; n < TN; n += 4) {
            float4 bv = *reinterpret_cast<const float4*>(wrow + n);
            b[n] = bv.x; b[n + 1] = bv.y; b[n + 2] = bv.z; b[n + 3] = bv.w;
        }
#pragma unroll
        for (int m = 0; m < TM; ++m)
#pragma unroll
            for (int n = 0; n < TN; ++n)
                acc[m][n] = fmaf(a[m], b[n], acc[m][n]);
    }

#pragma unroll
    for (int m = 0; m < TM; ++m) {
        int gr = row0 + ty + m * 16;
        if (gr < N) {
            float* orow = H + (size_t)gr * BN + tx * TN;
#pragma unroll
            for (int n = 0; n < TN; n += 4) {
                *reinterpret_cast<float4*>(orow + n) =
                    make_float4(acc[m][n], acc[m][n + 1], acc[m][n + 2], acc[m][n + 3]);
            }
        }
    }
}

// ===========================================================================
// CSR gather: one wave per dst node; lane owns 2 feature cols (float2).
// out[i,:] (+)= ( dinv[i]*sum_j dinv[s_j]*H[s_j,:] + dinv[i]^2*H[i,:] + b ) / 3
// No atomics: each node written by exactly one wave.
// ===========================================================================
template<int F>
__global__ __launch_bounds__(256) void gather_csr_kernel(
    float* __restrict__ out, const float* __restrict__ H,
    const float* __restrict__ dinv, const int* __restrict__ rp,
    const int* __restrict__ srcs, const float* __restrict__ bias,
    int N, int accum)
{
    int wave = threadIdx.x >> 6;
    int lane = threadIdx.x & 63;
    int i = blockIdx.x * 4 + wave;
    if (i >= N) return;
    int c = lane * 2;
    if (c >= F) return;                       // F=64: upper 32 lanes idle

    int beg = rp[i], end = rp[i + 1];
    float ax = 0.f, ay = 0.f;
    int j = beg;
    for (; j + 4 <= end; j += 4) {            // 4-way unroll: independent gathers
        int s0 = srcs[j], s1 = srcs[j + 1], s2 = srcs[j + 2], s3 = srcs[j + 3];
        float d0 = dinv[s0], d1 = dinv[s1], d2 = dinv[s2], d3 = dinv[s3];
        float2 h0 = *reinterpret_cast<const float2*>(H + (size_t)s0 * F + c);
        float2 h1 = *reinterpret_cast<const float2*>(H + (size_t)s1 * F + c);
        float2 h2 = *reinterpret_cast<const float2*>(H + (size_t)s2 * F + c);
        float2 h3 = *reinterpret_cast<const float2*>(H + (size_t)s3 * F + c);
        ax = fmaf(h0.x, d0, fmaf(h1.x, d1, fmaf(h2.x, d2, fmaf(h3.x, d3, ax))));
        ay = fmaf(h0.y, d0, fmaf(h1.y, d1, fmaf(h2.y, d2, fmaf(h3.y, d3, ay))));
    }
    for (; j < end; ++j) {
        int s = srcs[j];
        float d = dinv[s];
        float2 h = *reinterpret_cast<const float2*>(H + (size_t)s * F + c);
        ax = fmaf(h.x, d, ax);
        ay = fmaf(h.y, d, ay);
    }
    float di = dinv[i];
    float2 hs = *reinterpret_cast<const float2*>(H + (size_t)i * F + c);
    float2 bv = *reinterpret_cast<const float2*>(bias + c);
    float rx = (ax * di + hs.x * di * di + bv.x) * (1.0f / 3.0f);
    float ry = (ay * di + hs.y * di * di + bv.y) * (1.0f / 3.0f);
    float* op = out + (size_t)i * F + c;
    if (accum) { rx += op[0]; ry += op[1]; }
    *reinterpret_cast<float2*>(op) = make_float2(rx, ry);
}

// ===========================================================================
extern "C" void kernel_launch(void* const* d_in, const int* in_sizes, int n_in,
                              void* d_out, int out_size, void* d_ws, size_t ws_size,
                              hipStream_t stream) {
    const float* x     = (const float*)d_in[0];
    const int*   edges = (const int*)  d_in[1];
    const float* W1    = (const float*)d_in[2];
    const float* b1    = (const float*)d_in[3];
    const float* W2    = (const float*)d_in[4];
    const float* b2    = (const float*)d_in[5];
    float* out = (float*)d_out;

    const int N = in_sizes[0] / F_IN;
    const int E = in_sizes[1] / (T_REL * 2);

    // ---- workspace layout (256B-aligned chunks) ----
    auto align256 = [](size_t x) { return (x + 255) & ~(size_t)255; };
    char* p = (char*)d_ws;
    float* dinv    = (float*)p;  p += align256((size_t)T_REL * N * 4);
    int*   counts  = (int*)p;    p += align256((size_t)T_REL * N * 4);
    int*   rp      = (int*)p;    p += align256((size_t)T_REL * (N + 1) * 4);
    int*   cursor  = (int*)p;    p += align256((size_t)T_REL * N * 4);
    int*   parts   = (int*)p;    p += align256((size_t)T_REL * 64 * 4);
    int*   srcs    = (int*)p;    p += align256((size_t)T_REL * E * 4);
    float* Hbuf    = (float*)p;  p += align256((size_t)N * F_HID * 4);
    float* h1      = (float*)p;

    const int B = 256;
    const int CHUNK = 2048;
    const int nblk = (N + CHUNK - 1) / CHUNK;   // <= 64 for N=100k

    // ---- CSR build (once; reused by both layers) ----
    hipMemsetAsync(counts, 0, (size_t)T_REL * N * sizeof(int), stream);
    {
        dim3 g((E + B - 1) / B, T_REL);
        accum_deg_kernel<<<g, B, 0, stream>>>(counts, edges, E, N);
    }
    dinv_kernel<<<(T_REL * N + B - 1) / B, B, 0, stream>>>(dinv, counts, T_REL * N);
    {
        dim3 g(nblk, T_REL);
        scan_pass1<<<g, 256, 0, stream>>>(counts, parts, N, nblk);
        scan_partials<<<T_REL, 64, 0, stream>>>(parts, rp, nblk, N, E);
        scan_pass2<<<g, 256, 0, stream>>>(counts, parts, rp, cursor, N, nblk);
    }
    {
        dim3 g((E + B - 1) / B, T_REL);
        csr_build_kernel<<<g, B, 0, stream>>>(cursor, srcs, edges, E, N);
    }

    const int gather_grid = (N + 3) / 4;

    // ---- layer 1: h1 = mean_t( GCNConv(x@W1[t]) + b1[t] ) ----
    for (int t = 0; t < T_REL; ++t) {
        gemm_kernel<128, 8, false><<<(N + 127) / 128, 256, 0, stream>>>(
            x, W1 + (size_t)t * F_IN * F_HID, Hbuf, N);
        gather_csr_kernel<128><<<gather_grid, 256, 0, stream>>>(
            h1, Hbuf, dinv + (size_t)t * N, rp + (size_t)t * (N + 1),
            srcs + (size_t)t * E, b1 + (size_t)t * F_HID, N, t > 0 ? 1 : 0);
    }

    // ---- layer 2: out = mean_t( GCNConv(relu(h1)@W2[t]) + b2[t] ) ----
    for (int t = 0; t < T_REL; ++t) {
        gemm_kernel<64, 4, true><<<(N + 127) / 128, 256, 0, stream>>>(
            h1, W2 + (size_t)t * F_HID * F_OUT, Hbuf, N);
        gather_csr_kernel<64><<<gather_grid, 256, 0, stream>>>(
            out, Hbuf, dinv + (size_t)t * N, rp + (size_t)t * (N + 1),
            srcs + (size_t)t * E, b2 + (size_t)t * F_OUT, N, t > 0 ? 1 : 0);
    }
}